// Round 13
// baseline (213.101 us; speedup 1.0000x reference)
//
#include <hip/hip_runtime.h>
#include <hip/hip_bf16.h>

// Conv_SelfAttn — B=8, C=128, N=4096, C_QK=16. fp32 in/out.
// Round 17: persistent balanced attn.
//  attn: grid 256 (1 block/CU), 512 thr / 8 waves = (kr 0..3, half h 0..1).
//        Each block: 4 (b,qt) units — 2 concurrent (per half) x 2 serial.
//        Per-unit structure is EXACTLY r16 (passed, 105 us): full-C waves,
//        acc 4xf32x16, depth-2 named A/B prefetch, kappa-permuted V ->
//        identity P frags, fixed-max exp2 softmax, setprio on MFMA.
//        Fix targeted: r16's 1024-block grid at 3-resident -> 25% of time
//        at 1 block/CU straggler phase. Persistent grid = zero tail,
//        uniform packing, exact XCD/batch pinning (block i -> XCD i&7 = b).
//  qkv:  unchanged (passed 3x).
//
// Layout assumptions (32x32x16_bf16):
//   C/D: col = lane&31, row = (reg&3) + 8*(reg>>2) + 4*(lane>>5)   [m74/m101]
//   A  : m  = lane&31, k = 8*(lane>>5) + j (j=0..7 contiguous)
//   B  : n  = lane&31, k = 8*(lane>>5) + j
//
// ws (all bf16):
//   qw [B][128 tile][f(hi/lo)][lq][lr][8]   (2 MB, log2e pre-scaled)
//   kw [B][128 chunk][f(hi/lo)][lq][lr][8]  (2 MB)
//   vw [B][128 chunk][ct(4)][f(2)][lq][lr][8] (8 MB), key axis kappa-permuted

typedef __bf16 bf16x8 __attribute__((ext_vector_type(8)));
typedef __bf16 bf16x4 __attribute__((ext_vector_type(4)));
typedef float  f32x16 __attribute__((ext_vector_type(16)));

static constexpr int Bb = 8, Cc = 128, Nn = 4096, CQ = 16;

__device__ __forceinline__ f32x16 mfma32(bf16x8 a, bf16x8 b, f32x16 c) {
    return __builtin_amdgcn_mfma_f32_32x32x16_bf16(a, b, c, 0, 0, 0);
}
struct HL { __bf16 h, l; };
__device__ __forceinline__ HL hilo(float f) {
    HL r;
    r.h = (__bf16)f;
    r.l = (__bf16)(f - (float)r.h);
    return r;
}

// ---------------- Kernel 1: QKV projection (MFMA) ----------------
// grid (N/64, B), 384 threads (6 waves). Per block: x-tile 128ci x 64n.
// Staging by waves 0..3; MFMA roles: w0,w1 = QK(nh=w), w2..5 = V ct=w-2.
__global__ __launch_bounds__(384) void qkv_kernel(
    const float* __restrict__ x, const float* __restrict__ Wq,
    const float* __restrict__ Wk, const float* __restrict__ Wv,
    __bf16* __restrict__ qw, __bf16* __restrict__ kw, __bf16* __restrict__ vw)
{
    const int b = blockIdx.y, tb = blockIdx.x, n0 = tb * 64, t = threadIdx.x;
    const int wave = t >> 6, lane = t & 63, lr = lane & 31, lq = lane >> 5;

    __shared__ __bf16 xh[64][136], xl[64][136];   // x^T tile (n-major), hi/lo
    __shared__ __bf16 sc[4][32][40];              // per-V-wave transpose scratch

    // stage x: waves 0..3; thread owns (n = lane, 32 consecutive ci).
    // Each global load: 64 lanes x consecutive n = 256B fully coalesced.
    if (t < 256) {
        const int n = lane, ci0 = (t >> 6) * 32;
        #pragma unroll
        for (int g = 0; g < 4; ++g) {
            float v[8];
            #pragma unroll
            for (int k = 0; k < 8; ++k)
                v[k] = x[((size_t)(b * Cc + ci0 + g * 8 + k)) * Nn + n0 + n];
            bf16x8 h8, l8;
            #pragma unroll
            for (int k = 0; k < 8; ++k) { HL z = hilo(v[k]); h8[k] = z.h; l8[k] = z.l; }
            *(bf16x8*)&xh[n][ci0 + g * 8] = h8;
            *(bf16x8*)&xl[n][ci0 + g * 8] = l8;
        }
    }
    __syncthreads();

    if (wave < 2) {
        // ---- QK for n-half nh=wave: A-frags direct from global ----
        const int nh = wave;
        const float* wrow = (lr < 16) ? (Wq + (size_t)lr * Cc)
                                      : (Wk + (size_t)(lr - 16) * Cc);
        f32x16 acc = {};
        #pragma unroll
        for (int ks = 0; ks < 8; ++ks) {
            float4 w0 = *(const float4*)(wrow + ks * 16 + lq * 8);
            float4 w1 = *(const float4*)(wrow + ks * 16 + lq * 8 + 4);
            bf16x8 ah, al;
            HL z;
            z = hilo(w0.x); ah[0] = z.h; al[0] = z.l;
            z = hilo(w0.y); ah[1] = z.h; al[1] = z.l;
            z = hilo(w0.z); ah[2] = z.h; al[2] = z.l;
            z = hilo(w0.w); ah[3] = z.h; al[3] = z.l;
            z = hilo(w1.x); ah[4] = z.h; al[4] = z.l;
            z = hilo(w1.y); ah[5] = z.h; al[5] = z.l;
            z = hilo(w1.z); ah[6] = z.h; al[6] = z.l;
            z = hilo(w1.w); ah[7] = z.h; al[7] = z.l;
            bf16x8 bh = *(const bf16x8*)&xh[nh * 32 + lr][ks * 16 + lq * 8];
            bf16x8 bl = *(const bf16x8*)&xl[nh * 32 + lr][ks * 16 + lq * 8];
            acc = mfma32(ah, bh, acc);
            acc = mfma32(al, bh, acc);
            acc = mfma32(ah, bl, acc);
        }
        // vectorized fragment-major stores: rg 0,1 -> q ; rg 2,3 -> k
        const int tile = tb * 2 + nh;
        __bf16* qb = qw + (((size_t)b * 128 + tile) << 10);
        __bf16* kb = kw + (((size_t)b * 128 + tile) << 10);
        #pragma unroll
        for (int rg = 0; rg < 4; ++rg) {
            bf16x4 h4, l4;
            #pragma unroll
            for (int j = 0; j < 4; ++j) {
                float v = acc[rg * 4 + j];
                if (rg < 2) v *= 1.44269504089f;     // fold log2e into Q
                HL z = hilo(v);
                h4[j] = z.h; l4[j] = z.l;
            }
            const int off = (rg & 1) * 256 + lr * 8 + 4 * lq;
            __bf16* base = (rg < 2) ? qb : kb;
            *(bf16x4*)(base + off) = h4;
            *(bf16x4*)(base + 512 + off) = l4;
        }
    } else {
        // ---- V: wave owns c-tile ct for BOTH n-halves ----
        const int ct = wave - 2;
        const int klr = (lr & ~12) | ((lr & 4) << 1) | ((lr & 8) >> 1); // kappa
        for (int nh = 0; nh < 2; ++nh) {
            f32x16 acc = {};
            #pragma unroll
            for (int ks = 0; ks < 8; ++ks) {
                const float* wp = Wv + (size_t)(ct * 32 + lr) * Cc + ks * 16 + lq * 8;
                float4 w0 = *(const float4*)wp;
                float4 w1 = *(const float4*)(wp + 4);
                bf16x8 a = { (__bf16)w0.x, (__bf16)w0.y, (__bf16)w0.z, (__bf16)w0.w,
                             (__bf16)w1.x, (__bf16)w1.y, (__bf16)w1.z, (__bf16)w1.w };
                bf16x8 bh = *(const bf16x8*)&xh[nh * 32 + lr][ks * 16 + lq * 8];
                acc = mfma32(a, bh, acc);
            }
            // transpose via wave-private LDS scratch, key axis kappa-permuted
            #pragma unroll
            for (int r = 0; r < 16; ++r) {
                int crow = (r & 3) + 8 * (r >> 2) + 4 * lq;
                sc[ct][crow][klr] = (__bf16)acc[r];
            }
            const int chunk = tb * 2 + nh;
            __bf16* vb = vw + (((size_t)b * 128 + chunk) << 12) + ct * 1024;
            #pragma unroll
            for (int u = 0; u < 2; ++u) {
                bf16x8 row = *(const bf16x8*)&sc[ct][lr][u * 16 + lq * 8];
                *(bf16x8*)(vb + u * 512 + lane * 8) = row;
            }
        }
    }
}

// ---------------- Kernel 2: persistent balanced full-C flash attention ----
// grid 256 (1 block/CU) x 512 thr. Block i: b = i&7 (XCD-pinned), base
// query group qt0 = (i>>3)*4. Wave (kr = w&3, h = w>>2). Two units run
// concurrently (one per half h), two serial iterations -> 4 units/block.
__global__ __launch_bounds__(512, 2) void attn_kernel(
    const float* __restrict__ x, const __bf16* __restrict__ qw,
    const __bf16* __restrict__ kw, const __bf16* __restrict__ vw,
    const float* __restrict__ gamma, float* __restrict__ out)
{
    const int i = blockIdx.x;
    const int b = i & 7;                 // block i -> XCD i&7 -> batch b
    const int qt0 = (i >> 3) * 4;        // 4 query tiles per block
    const int t = threadIdx.x;
    const int wave = t >> 6, lane = t & 63, lr = lane & 31, lq = lane >> 5;
    const int kr = wave & 3, hh = wave >> 2;

    __shared__ float accbuf[2][32][129];
    __shared__ float lbuf[2][32];

    const float g = gamma[0];
    const __bf16* kwb = kw + (((size_t)b * 128) << 10);
    const __bf16* vwb = vw + (((size_t)b * 128) << 12);
    const int c0 = kr * 32;              // this wave's first key chunk

    for (int u = 0; u < 2; ++u) {
        const int qt = qt0 + u * 2 + hh;

        // Q fragment (pre-split hi/lo, pre-scaled): dense 16B loads
        const __bf16* qb = qw + (((size_t)b * 128 + qt) << 10) + lane * 8;
        const bf16x8 qhi = *(const bf16x8*)qb;
        const bf16x8 qlo = *(const bf16x8*)(qb + 512);

        const __bf16* kp = kwb + ((size_t)c0 << 10) + lane * 8;
        const __bf16* vp = vwb + ((size_t)c0 << 12) + lane * 8;

        f32x16 acc[4] = {{}, {}, {}, {}};
        float l_part = 0.f;

        // register set A <- chunk c0 (K hi/lo + full-C 8 V fragments)
        bf16x8 akh = *(const bf16x8*)kp, akl = *(const bf16x8*)(kp + 512);
        bf16x8 av[8], bv[8];
        #pragma unroll
        for (int v8 = 0; v8 < 8; ++v8) av[v8] = *(const bf16x8*)(vp + v8 * 512);
        bf16x8 bkh, bkl;                 // register set B

        auto body = [&](const bf16x8& Kh, const bf16x8& Kl, const bf16x8 (&V)[8]) {
            // S^T = K * Q^T (one 32x32 tile, hi/lo 3-term)
            f32x16 s = {};
            __builtin_amdgcn_s_setprio(1);
            s = mfma32(Kh, qhi, s);
            s = mfma32(Kl, qhi, s);
            s = mfma32(Kh, qlo, s);
            __builtin_amdgcn_s_setprio(0);

            // p = 2^s (log2 domain; fixed max)
            float p[16];
            #pragma unroll
            for (int r = 0; r < 16; ++r) p[r] = __builtin_amdgcn_exp2f(s[r]);
            l_part += ((((p[0] + p[1]) + (p[2] + p[3])) + ((p[4] + p[5]) + (p[6] + p[7])))
                     + (((p[8] + p[9]) + (p[10] + p[11])) + ((p[12] + p[13]) + (p[14] + p[15]))));

            // P fragments: identity order thanks to kappa-permuted V storage
            bf16x8 F0, F1;
            #pragma unroll
            for (int j = 0; j < 8; ++j) {
                F0[j] = (__bf16)p[j];
                F1[j] = (__bf16)p[8 + j];
            }

            // O^T += V^T * P (full C: 4 c-tiles)
            __builtin_amdgcn_s_setprio(1);
            #pragma unroll
            for (int ct = 0; ct < 4; ++ct) {
                acc[ct] = mfma32(V[2 * ct],     F0, acc[ct]);
                acc[ct] = mfma32(V[2 * ct + 1], F1, acc[ct]);
            }
            __builtin_amdgcn_s_setprio(0);
        };

        // 2x-unrolled main loop: 32 chunks = preload + 15x2 + 2 peeled
        for (int it = 0; it < 15; ++it) {
            kp += 1024; vp += 4096;
            bkh = *(const bf16x8*)kp; bkl = *(const bf16x8*)(kp + 512);
            #pragma unroll
            for (int v8 = 0; v8 < 8; ++v8) bv[v8] = *(const bf16x8*)(vp + v8 * 512);
            body(akh, akl, av);
            kp += 1024; vp += 4096;
            akh = *(const bf16x8*)kp; akl = *(const bf16x8*)(kp + 512);
            #pragma unroll
            for (int v8 = 0; v8 < 8; ++v8) av[v8] = *(const bf16x8*)(vp + v8 * 512);
            body(bkh, bkl, bv);
        }
        kp += 1024; vp += 4096;
        bkh = *(const bf16x8*)kp; bkl = *(const bf16x8*)(kp + 512);
        #pragma unroll
        for (int v8 = 0; v8 < 8; ++v8) bv[v8] = *(const bf16x8*)(vp + v8 * 512);
        body(akh, akl, av);              // chunk 30
        body(bkh, bkl, bv);              // chunk 31

        // pair-sum of softmax denominator (each lane summed its 16-key half)
        l_part += __shfl_xor(l_part, 32);

        // -------- merge 4 kr-partials per half (pure sums) --------
        if (kr == 0) {
            #pragma unroll
            for (int ct = 0; ct < 4; ++ct)
                #pragma unroll
                for (int r = 0; r < 16; ++r) {
                    int c = (r & 3) + 8 * (r >> 2) + 4 * lq + 32 * ct;
                    accbuf[hh][lr][c] = acc[ct][r];
                }
            if (lane < 32) lbuf[hh][lr] = l_part;
        }
        __syncthreads();
        if (kr != 0) {
            #pragma unroll
            for (int ct = 0; ct < 4; ++ct)
                #pragma unroll
                for (int r = 0; r < 16; ++r) {
                    int c = (r & 3) + 8 * (r >> 2) + 4 * lq + 32 * ct;
                    atomicAdd(&accbuf[hh][lr][c], acc[ct][r]);
                }
            if (lane < 32) atomicAdd(&lbuf[hh][lr], l_part);
        }
        __syncthreads();

        // ---- epilogue: out = x + gamma * O / l (coalesced along n) ----
        {
            const int he = t >> 8;           // which half's unit
            const int tt = t & 255;
            const int q = tt & 31, cg = tt >> 5;   // q 0..31, cg 0..7
            const float linv = 1.0f / lbuf[he][q];
            const int n0b = (qt0 + u * 2 + he) * 32;
            #pragma unroll
            for (int ii = 0; ii < 16; ++ii) {
                int c = cg + 8 * ii;
                size_t idx = ((size_t)(b * Cc + c)) * Nn + n0b + q;
                out[idx] = x[idx] + g * accbuf[he][q][c] * linv;
            }
        }
        __syncthreads();                 // accbuf reuse guard for next unit
    }
}

extern "C" void kernel_launch(void* const* d_in, const int* in_sizes, int n_in,
                              void* d_out, int out_size, void* d_ws, size_t ws_size,
                              hipStream_t stream) {
    const float* x  = (const float*)d_in[0];
    const float* Wq = (const float*)d_in[1];
    const float* Wk = (const float*)d_in[2];
    const float* Wv = (const float*)d_in[3];
    const float* gm = (const float*)d_in[4];

    __bf16* qw = (__bf16*)d_ws;                        // 2 MB
    __bf16* kw = qw + (size_t)Bb * 128 * 1024;         // 2 MB
    __bf16* vw = kw + (size_t)Bb * 128 * 1024;         // 8 MB

    qkv_kernel<<<dim3(Nn / 64, Bb), 384, 0, stream>>>(x, Wq, Wk, Wv, qw, kw, vw);
    attn_kernel<<<dim3(256), 512, 0, stream>>>(x, qw, kw, vw, gm,
                                               (float*)d_out);
}

// Round 14
// 180.738 us; speedup vs baseline: 1.1791x; 1.1791x over previous
//
#include <hip/hip_runtime.h>
#include <hip/hip_bf16.h>

// Conv_SelfAttn — B=8, C=128, N=4096, C_QK=16. fp32 in/out.
// Round 18: hoist W conversion out of qkv (the ~72 us gap was 512 blocks
// re-running ~450 VALU/thread of W->bf16 hi/lo conversion; W is
// block-invariant).
//  wprep: one-shot kernel (grid 16) -> wqk[2][32][128] (stacked [Wq;Wk]
//         hi/lo) + wvh[128][128] (hi) in ws. ~2 us.
//  qkv:   W fragment loads become bare bf16x8 loads (L1-hot). Otherwise
//         byte-identical to r14/r16 qkv (passed 4x).
//  attn:  EXACT r16 kernel (passed, 105 us, VGPR 96, no spill). r17's
//         persistent variant spilled (WRITE 16.4->26.1 MB) — reverted.
//
// Layout assumptions (32x32x16_bf16):
//   C/D: col = lane&31, row = (reg&3) + 8*(reg>>2) + 4*(lane>>5)   [m74/m101]
//   A  : m  = lane&31, k = 8*(lane>>5) + j (j=0..7 contiguous)
//   B  : n  = lane&31, k = 8*(lane>>5) + j
//
// ws (all bf16):
//   qw [B][128 tile][f(hi/lo)][lq][lr][8]   (2 MB, log2e pre-scaled)
//   kw [B][128 chunk][f(hi/lo)][lq][lr][8]  (2 MB)
//   vw [B][128 chunk][ct(4)][f(2)][lq][lr][8] (8 MB), key axis kappa-permuted
//   wqk [f(2)][32][128] (16 KB) | wvh [128][128] (32 KB)

typedef __bf16 bf16x8 __attribute__((ext_vector_type(8)));
typedef __bf16 bf16x4 __attribute__((ext_vector_type(4)));
typedef float  f32x16 __attribute__((ext_vector_type(16)));

static constexpr int Bb = 8, Cc = 128, Nn = 4096, CQ = 16;

__device__ __forceinline__ f32x16 mfma32(bf16x8 a, bf16x8 b, f32x16 c) {
    return __builtin_amdgcn_mfma_f32_32x32x16_bf16(a, b, c, 0, 0, 0);
}
struct HL { __bf16 h, l; };
__device__ __forceinline__ HL hilo(float f) {
    HL r;
    r.h = (__bf16)f;
    r.l = (__bf16)(f - (float)r.h);
    return r;
}

// ---------------- Kernel 0: one-shot W conversion ----------------
// grid 16 x 256 thr. wqk: rows 0-15 = Wq, 16-31 = Wk; hi plane then lo.
__global__ __launch_bounds__(256) void wprep_kernel(
    const float* __restrict__ Wq, const float* __restrict__ Wk,
    const float* __restrict__ Wv, __bf16* __restrict__ wqk,
    __bf16* __restrict__ wvh)
{
    const int t = blockIdx.x * 256 + threadIdx.x;   // 0..4095
    if (t < 2048) {
        const int o = t >> 7, ci = t & 127;
        HL zq = hilo(Wq[t]);
        wqk[o * 128 + ci] = zq.h;
        wqk[4096 + o * 128 + ci] = zq.l;
        HL zk = hilo(Wk[t]);
        wqk[(16 + o) * 128 + ci] = zk.h;
        wqk[4096 + (16 + o) * 128 + ci] = zk.l;
    }
    #pragma unroll
    for (int i = 0; i < 4; ++i) {
        int idx = t + i * 4096;
        wvh[idx] = (__bf16)Wv[idx];
    }
}

// ---------------- Kernel 1: QKV projection (MFMA) ----------------
// grid (N/64, B), 384 threads (6 waves). Per block: x-tile 128ci x 64n.
// Staging by waves 0..3; MFMA roles: w0,w1 = QK(nh=w), w2..5 = V ct=w-2.
// W fragments from pre-converted wqk/wvh (bare bf16x8 loads, L1-hot).
__global__ __launch_bounds__(384) void qkv_kernel(
    const float* __restrict__ x, const __bf16* __restrict__ wqk,
    const __bf16* __restrict__ wvh,
    __bf16* __restrict__ qw, __bf16* __restrict__ kw, __bf16* __restrict__ vw)
{
    const int b = blockIdx.y, tb = blockIdx.x, n0 = tb * 64, t = threadIdx.x;
    const int wave = t >> 6, lane = t & 63, lr = lane & 31, lq = lane >> 5;

    __shared__ __bf16 xh[64][136], xl[64][136];   // x^T tile (n-major), hi/lo
    __shared__ __bf16 sc[4][32][40];              // per-V-wave transpose scratch

    // stage x: waves 0..3; thread owns (n = lane, 32 consecutive ci).
    if (t < 256) {
        const int n = lane, ci0 = (t >> 6) * 32;
        #pragma unroll
        for (int g = 0; g < 4; ++g) {
            float v[8];
            #pragma unroll
            for (int k = 0; k < 8; ++k)
                v[k] = x[((size_t)(b * Cc + ci0 + g * 8 + k)) * Nn + n0 + n];
            bf16x8 h8, l8;
            #pragma unroll
            for (int k = 0; k < 8; ++k) { HL z = hilo(v[k]); h8[k] = z.h; l8[k] = z.l; }
            *(bf16x8*)&xh[n][ci0 + g * 8] = h8;
            *(bf16x8*)&xl[n][ci0 + g * 8] = l8;
        }
    }
    __syncthreads();

    if (wave < 2) {
        // ---- QK for n-half nh=wave: pre-converted stacked [Wq;Wk] row lr ----
        const int nh = wave;
        const __bf16* wrh = wqk + lr * 128;
        const __bf16* wrl = wqk + 4096 + lr * 128;
        f32x16 acc = {};
        #pragma unroll
        for (int ks = 0; ks < 8; ++ks) {
            bf16x8 ah = *(const bf16x8*)(wrh + ks * 16 + lq * 8);
            bf16x8 al = *(const bf16x8*)(wrl + ks * 16 + lq * 8);
            bf16x8 bh = *(const bf16x8*)&xh[nh * 32 + lr][ks * 16 + lq * 8];
            bf16x8 bl = *(const bf16x8*)&xl[nh * 32 + lr][ks * 16 + lq * 8];
            acc = mfma32(ah, bh, acc);
            acc = mfma32(al, bh, acc);
            acc = mfma32(ah, bl, acc);
        }
        // vectorized fragment-major stores: rg 0,1 -> q ; rg 2,3 -> k
        const int tile = tb * 2 + nh;
        __bf16* qb = qw + (((size_t)b * 128 + tile) << 10);
        __bf16* kb = kw + (((size_t)b * 128 + tile) << 10);
        #pragma unroll
        for (int rg = 0; rg < 4; ++rg) {
            bf16x4 h4, l4;
            #pragma unroll
            for (int j = 0; j < 4; ++j) {
                float v = acc[rg * 4 + j];
                if (rg < 2) v *= 1.44269504089f;     // fold log2e into Q
                HL z = hilo(v);
                h4[j] = z.h; l4[j] = z.l;
            }
            const int off = (rg & 1) * 256 + lr * 8 + 4 * lq;
            __bf16* base = (rg < 2) ? qb : kb;
            *(bf16x4*)(base + off) = h4;
            *(bf16x4*)(base + 512 + off) = l4;
        }
    } else {
        // ---- V: wave owns c-tile ct for BOTH n-halves; pre-converted Wv ----
        const int ct = wave - 2;
        const int klr = (lr & ~12) | ((lr & 4) << 1) | ((lr & 8) >> 1); // kappa
        const __bf16* wvr = wvh + (size_t)(ct * 32 + lr) * 128;
        for (int nh = 0; nh < 2; ++nh) {
            f32x16 acc = {};
            #pragma unroll
            for (int ks = 0; ks < 8; ++ks) {
                bf16x8 a  = *(const bf16x8*)(wvr + ks * 16 + lq * 8);
                bf16x8 bh = *(const bf16x8*)&xh[nh * 32 + lr][ks * 16 + lq * 8];
                acc = mfma32(a, bh, acc);
            }
            // transpose via wave-private LDS scratch, key axis kappa-permuted
            #pragma unroll
            for (int r = 0; r < 16; ++r) {
                int crow = (r & 3) + 8 * (r >> 2) + 4 * lq;
                sc[ct][crow][klr] = (__bf16)acc[r];
            }
            const int chunk = tb * 2 + nh;
            __bf16* vb = vw + (((size_t)b * 128 + chunk) << 12) + ct * 1024;
            #pragma unroll
            for (int u = 0; u < 2; ++u) {
                bf16x8 row = *(const bf16x8*)&sc[ct][lr][u * 16 + lq * 8];
                *(bf16x8*)(vb + u * 512 + lane * 8) = row;
            }
        }
    }
}

// ---------------- Kernel 2: 4-wave full-C flash attention ----------------
// grid 1024 x 256 thr. Block -> (b = bid&7 [XCD-pinned], 32 queries).
// Wave w = kr (key chunks kr*32..+32), FULL C=128 (acc 4 x f32x16).
// Fixed softmax max (m=0, exp2 domain). Key-permuted V -> identity P frags.
// K+V double-buffered via 2x-unrolled loop with named A/B register sets.
// launch_bounds(256,2): 256-reg budget; working set ~160 -> no spill.
__global__ __launch_bounds__(256, 2) void attn_kernel(
    const float* __restrict__ x, const __bf16* __restrict__ qw,
    const __bf16* __restrict__ kw, const __bf16* __restrict__ vw,
    const float* __restrict__ gamma, float* __restrict__ out)
{
    const int h = blockIdx.x;
    const int b = h & 7;                 // consecutive blocks -> different XCDs
    const int qt = h >> 3;               // query tile (32 queries)
    const int t = threadIdx.x;
    const int wave = t >> 6, lane = t & 63, lr = lane & 31, lq = lane >> 5;
    const int kr = wave;                 // 0..3

    __shared__ float accbuf[32][129];
    __shared__ float lbuf[32];

    // Q fragment (pre-split hi/lo, pre-scaled): dense 16B loads
    const __bf16* qb = qw + (((size_t)b * 128 + qt) << 10) + lane * 8;
    const bf16x8 qhi = *(const bf16x8*)qb;
    const bf16x8 qlo = *(const bf16x8*)(qb + 512);

    const int c0 = kr * 32;              // this wave's first key chunk
    const __bf16* kp = kw + (((size_t)b * 128 + c0) << 10) + lane * 8;
    const __bf16* vp = vw + (((size_t)b * 128 + c0) << 12) + lane * 8;

    f32x16 acc[4] = {{}, {}, {}, {}};
    float l_part = 0.f;

    // register set A <- chunk c0 (K hi/lo + full-C 8 V fragments)
    bf16x8 akh = *(const bf16x8*)kp, akl = *(const bf16x8*)(kp + 512);
    bf16x8 av[8], bv[8];
    #pragma unroll
    for (int u = 0; u < 8; ++u) av[u] = *(const bf16x8*)(vp + u * 512);
    bf16x8 bkh, bkl;                     // register set B

    auto body = [&](const bf16x8& Kh, const bf16x8& Kl, const bf16x8 (&V)[8]) {
        // S^T = K * Q^T (one 32x32 tile, hi/lo 3-term)
        f32x16 s = {};
        __builtin_amdgcn_s_setprio(1);
        s = mfma32(Kh, qhi, s);
        s = mfma32(Kl, qhi, s);
        s = mfma32(Kh, qlo, s);
        __builtin_amdgcn_s_setprio(0);

        // p = 2^s (log2 domain; fixed max)
        float p[16];
        #pragma unroll
        for (int r = 0; r < 16; ++r) p[r] = __builtin_amdgcn_exp2f(s[r]);
        l_part += ((((p[0] + p[1]) + (p[2] + p[3])) + ((p[4] + p[5]) + (p[6] + p[7])))
                 + (((p[8] + p[9]) + (p[10] + p[11])) + ((p[12] + p[13]) + (p[14] + p[15]))));

        // P fragments: identity order thanks to kappa-permuted V storage
        bf16x8 F0, F1;
        #pragma unroll
        for (int j = 0; j < 8; ++j) {
            F0[j] = (__bf16)p[j];
            F1[j] = (__bf16)p[8 + j];
        }

        // O^T += V^T * P (full C: 4 c-tiles)
        __builtin_amdgcn_s_setprio(1);
        #pragma unroll
        for (int ct = 0; ct < 4; ++ct) {
            acc[ct] = mfma32(V[2 * ct],     F0, acc[ct]);
            acc[ct] = mfma32(V[2 * ct + 1], F1, acc[ct]);
        }
        __builtin_amdgcn_s_setprio(0);
    };

    // 2x-unrolled main loop: 32 chunks = preload + 15x2 + 2 peeled
    for (int it = 0; it < 15; ++it) {
        kp += 1024; vp += 4096;
        bkh = *(const bf16x8*)kp; bkl = *(const bf16x8*)(kp + 512);
        #pragma unroll
        for (int u = 0; u < 8; ++u) bv[u] = *(const bf16x8*)(vp + u * 512);
        body(akh, akl, av);
        kp += 1024; vp += 4096;
        akh = *(const bf16x8*)kp; akl = *(const bf16x8*)(kp + 512);
        #pragma unroll
        for (int u = 0; u < 8; ++u) av[u] = *(const bf16x8*)(vp + u * 512);
        body(bkh, bkl, bv);
    }
    kp += 1024; vp += 4096;
    bkh = *(const bf16x8*)kp; bkl = *(const bf16x8*)(kp + 512);
    #pragma unroll
    for (int u = 0; u < 8; ++u) bv[u] = *(const bf16x8*)(vp + u * 512);
    body(akh, akl, av);                  // chunk 30
    body(bkh, bkl, bv);                  // chunk 31

    // pair-sum of softmax denominator (each lane summed its 16-key half)
    l_part += __shfl_xor(l_part, 32);

    // -------- merge 4 kr-partials (pure sums) --------
    if (kr == 0) {
        #pragma unroll
        for (int ct = 0; ct < 4; ++ct)
            #pragma unroll
            for (int r = 0; r < 16; ++r) {
                int c = (r & 3) + 8 * (r >> 2) + 4 * lq + 32 * ct;
                accbuf[lr][c] = acc[ct][r];
            }
        if (lane < 32) lbuf[lr] = l_part;
    }
    __syncthreads();
    if (kr != 0) {
        #pragma unroll
        for (int ct = 0; ct < 4; ++ct)
            #pragma unroll
            for (int r = 0; r < 16; ++r) {
                int c = (r & 3) + 8 * (r >> 2) + 4 * lq + 32 * ct;
                atomicAdd(&accbuf[lr][c], acc[ct][r]);
            }
        if (lane < 32) atomicAdd(&lbuf[lr], l_part);
    }
    __syncthreads();

    // -------- epilogue: out = x + gamma * O / l (coalesced along n) --------
    const float g = gamma[0];
    const int q = t & 31, cg = t >> 5;   // q 0..31, cg 0..7
    const float linv = 1.0f / lbuf[q];
    const int n0b = qt * 32;
    #pragma unroll
    for (int i = 0; i < 16; ++i) {
        int c = cg + 8 * i;
        size_t idx = ((size_t)(b * Cc + c)) * Nn + n0b + q;
        out[idx] = x[idx] + g * accbuf[q][c] * linv;
    }
}

extern "C" void kernel_launch(void* const* d_in, const int* in_sizes, int n_in,
                              void* d_out, int out_size, void* d_ws, size_t ws_size,
                              hipStream_t stream) {
    const float* x  = (const float*)d_in[0];
    const float* Wq = (const float*)d_in[1];
    const float* Wk = (const float*)d_in[2];
    const float* Wv = (const float*)d_in[3];
    const float* gm = (const float*)d_in[4];

    __bf16* qw  = (__bf16*)d_ws;                       // 2 MB
    __bf16* kw  = qw + (size_t)Bb * 128 * 1024;        // 2 MB
    __bf16* vw  = kw + (size_t)Bb * 128 * 1024;        // 8 MB
    __bf16* wqk = vw + (size_t)Bb * 128 * 4096;        // 16 KB
    __bf16* wvh = wqk + 8192;                          // 32 KB

    wprep_kernel<<<dim3(16), 256, 0, stream>>>(Wq, Wk, Wv, wqk, wvh);
    qkv_kernel<<<dim3(Nn / 64, Bb), 384, 0, stream>>>(x, wqk, wvh, qw, kw, vw);
    attn_kernel<<<dim3(Nn / 32 * Bb), 256, 0, stream>>>(x, qw, kw, vw, gm,
                                                        (float*)d_out);
}